// Round 2
// baseline (153.069 us; speedup 1.0000x reference)
//
#include <hip/hip_runtime.h>
#include <stdint.h>

#define N_NODES 2048
#define N_BATCH 4
#define ROWS_PER_BLOCK 8
#define THREADS 512   // 8 waves, one row per wave

__device__ __forceinline__ uint32_t bf16rn(float x) {
    uint32_t u = __float_as_uint(x);
    u += 0x7fffu + ((u >> 16) & 1u);
    return u >> 16;
}

__global__ __launch_bounds__(THREADS, 2) void kuramoto_kernel(
    const float* __restrict__ theta,
    const float* __restrict__ gamma,
    const float* __restrict__ W,
    const float* __restrict__ alpha,
    float* __restrict__ out)
{
    // 32 KB: per j, 4 dwords, dword d = (bf16(cos th_jd)<<16) | bf16(sin th_jd)
    __shared__ uint4 table[N_NODES];
    // 32 KB: per-wave transpose-reduction scratch, XOR-swizzled (<=2 lanes/bank)
    __shared__ float red[ROWS_PER_BLOCK * 16 * 64];

    const int tid  = threadIdx.x;
    const int lane = tid & 63;
    const int wave = tid >> 6;
    const int b    = blockIdx.x >> 8;                       // 256 blocks per batch
    const int i    = ((blockIdx.x & 255) * ROWS_PER_BLOCK) + wave;  // row in batch

    // ---- Phase 1: stage sin/cos(theta[b,:,:]) into LDS, bf16-packed ----
    const float* thb = theta + (size_t)b * (N_NODES * 4);
    #pragma unroll
    for (int g = 0; g < N_NODES / THREADS; ++g) {
        const int j = tid + g * THREADS;
        const float4 u = *(const float4*)(thb + (size_t)j * 4);  // 16B coalesced
        const float th[4] = {u.x, u.y, u.z, u.w};
        uint32_t p[4];
        #pragma unroll
        for (int d = 0; d < 4; ++d) {
            float s, c;
            __sincosf(th[d], &s, &c);
            p[d] = (bf16rn(c) << 16) | bf16rn(s);
        }
        table[j] = make_uint4(p[0], p[1], p[2], p[3]);
    }
    __syncthreads();

    // ---- Phase 2: accumulate over j (lane l owns j = it*64 + l) ----
    const size_t rowbase = ((size_t)b * N_NODES + i) * N_NODES;
    const float* Wr = W + rowbase;
    const float* Ar = alpha + rowbase;

    float aAs[4] = {0.f, 0.f, 0.f, 0.f};
    float aAc[4] = {0.f, 0.f, 0.f, 0.f};
    float aBs[4] = {0.f, 0.f, 0.f, 0.f};
    float aBc[4] = {0.f, 0.f, 0.f, 0.f};

    #pragma unroll 8
    for (int it = 0; it < N_NODES / 64; ++it) {
        const int j = it * 64 + lane;                      // 256B/wave contiguous loads
        const float w = Wr[j];
        const float a = Ar[j];
        float sa, ca;
        __sincosf(a, &sa, &ca);
        const float A  = w * ca;   // W*cos(alpha)
        const float Bq = w * sa;   // W*sin(alpha)
        const uint4 t = table[j];                          // one ds_read_b128
        const uint32_t tw[4] = {t.x, t.y, t.z, t.w};
        #pragma unroll
        for (int d = 0; d < 4; ++d) {
            const float s = __uint_as_float(tw[d] << 16);
            const float c = __uint_as_float(tw[d] & 0xffff0000u);
            aAs[d] = fmaf(A,  s, aAs[d]);
            aAc[d] = fmaf(A,  c, aAc[d]);
            aBs[d] = fmaf(Bq, s, aBs[d]);
            aBc[d] = fmaf(Bq, c, aBc[d]);
        }
    }

    // ---- Reduction: LDS transpose, XOR-swizzled so every access is <=2 lanes/bank ----
    float* myred = red + wave * (16 * 64);
    #pragma unroll
    for (int d = 0; d < 4; ++d) {
        myred[(0 * 4 + d) * 64 + (lane ^ (0 * 4 + d))] = aAs[d];
        myred[(1 * 4 + d) * 64 + (lane ^ (1 * 4 + d))] = aAc[d];
        myred[(2 * 4 + d) * 64 + (lane ^ (2 * 4 + d))] = aBs[d];
        myred[(3 * 4 + d) * 64 + (lane ^ (3 * 4 + d))] = aBc[d];
    }
    __syncthreads();

    const int v   = lane & 15;   // which accumulator (0-3 As, 4-7 Ac, 8-11 Bs, 12-15 Bc)
    const int seg = lane >> 4;   // which 16-lane segment this lane sums
    float sum = 0.0f;
    #pragma unroll
    for (int m = 0; m < 16; ++m)
        sum += myred[v * 64 + ((seg * 16 + m) ^ v)];
    sum += __shfl_xor(sum, 16, 64);
    sum += __shfl_xor(sum, 32, 64);
    // now every lane holds the full row-sum for accumulator v = lane & 15

    const int d = lane & 3;
    const float As = __shfl(sum,      d, 64);
    const float Ac = __shfl(sum,  4 + d, 64);
    const float Bs = __shfl(sum,  8 + d, 64);
    const float Bc = __shfl(sum, 12 + d, 64);

    if (lane < 4) {
        // exact s_i, c_i from float32 theta (not the bf16 table) for accuracy
        const float th_i = thb[(size_t)i * 4 + d];
        float s_i, c_i;
        __sincosf(th_i, &s_i, &c_i);
        const float coup = (c_i * As - s_i * Ac - c_i * Bc - s_i * Bs)
                           * (1.0f / (float)N_NODES);
        const size_t oidx = ((size_t)b * N_NODES + i) * 4 + d;
        const float g = gamma[oidx];
        const float t = g + coup;   // theta + (gamma-theta) + coupling  (DT=ATTR=1)
        float s2 = t * t;
        s2 += __shfl_xor(s2, 1, 64);
        s2 += __shfl_xor(s2, 2, 64);
        const float nrm = sqrtf(s2);
        const float inv = 1.0f / fmaxf(nrm, 1e-6f);
        out[oidx] = t * inv;
    }
}

extern "C" void kernel_launch(void* const* d_in, const int* in_sizes, int n_in,
                              void* d_out, int out_size, void* d_ws, size_t ws_size,
                              hipStream_t stream) {
    const float* theta = (const float*)d_in[0];
    const float* gamma = (const float*)d_in[1];
    const float* W     = (const float*)d_in[2];
    const float* alpha = (const float*)d_in[3];
    float* out = (float*)d_out;

    const int grid = (N_BATCH * N_NODES) / ROWS_PER_BLOCK;  // 1024 blocks
    hipLaunchKernelGGL(kuramoto_kernel, dim3(grid), dim3(THREADS), 0, stream,
                       theta, gamma, W, alpha, out);
}

// Round 3
// 152.364 us; speedup vs baseline: 1.0046x; 1.0046x over previous
//
#include <hip/hip_runtime.h>
#include <stdint.h>

#define N_NODES 2048
#define N_BATCH 4
#define ROWS_PER_BLOCK 8
#define THREADS 512   // 8 waves, one row per wave

__device__ __forceinline__ uint32_t bf16rn(float x) {
    uint32_t u = __float_as_uint(x);
    u += 0x7fffu + ((u >> 16) & 1u);
    return u >> 16;
}

// LDS = 32 KB table only -> 4 blocks/CU (32 waves/CU, 100% occupancy cap).
// __launch_bounds__(512, 8): 8 waves/SIMD -> VGPR capped at 64.
__global__ __launch_bounds__(THREADS, 8) void kuramoto_kernel(
    const float* __restrict__ theta,
    const float* __restrict__ gamma,
    const float* __restrict__ W,
    const float* __restrict__ alpha,
    float* __restrict__ out)
{
    // per j, 4 dwords: dword d = (bf16(cos th_jd)<<16) | bf16(sin th_jd)
    __shared__ uint4 table[N_NODES];

    const int tid  = threadIdx.x;
    const int lane = tid & 63;
    const int wave = tid >> 6;
    const int b    = blockIdx.x >> 8;                       // 256 blocks per batch
    const int i    = ((blockIdx.x & 255) * ROWS_PER_BLOCK) + wave;  // row in batch

    // ---- Phase 1: stage sin/cos(theta[b,:,:]) into LDS, bf16-packed ----
    const float* thb = theta + (size_t)b * (N_NODES * 4);
    #pragma unroll
    for (int g = 0; g < N_NODES / THREADS; ++g) {
        const int j = tid + g * THREADS;
        const float4 u = *(const float4*)(thb + (size_t)j * 4);  // 16B coalesced
        const float th[4] = {u.x, u.y, u.z, u.w};
        uint32_t p[4];
        #pragma unroll
        for (int d = 0; d < 4; ++d) {
            float s, c;
            __sincosf(th[d], &s, &c);
            p[d] = (bf16rn(c) << 16) | bf16rn(s);
        }
        table[j] = make_uint4(p[0], p[1], p[2], p[3]);  // lane stride 16B: conflict-free
    }
    __syncthreads();

    // ---- Phase 2: complex accumulation over j (lane l owns j = it*64 + l) ----
    // coupling_d = c_i*im_d - s_i*re_d, with
    //   im_d = sum_j (A*s_jd - B*c_jd),  re_d = sum_j (A*c_jd + B*s_jd)
    //   A = W*cos(alpha), B = W*sin(alpha)
    // (identical arithmetic to the reference's As/Ac/Bs/Bc form, 8 accs not 16)
    const size_t rowbase = ((size_t)b * N_NODES + i) * N_NODES;
    const float* Wr = W + rowbase;
    const float* Ar = alpha + rowbase;

    float re[4] = {0.f, 0.f, 0.f, 0.f};
    float im[4] = {0.f, 0.f, 0.f, 0.f};

    #pragma unroll 8
    for (int it = 0; it < N_NODES / 64; ++it) {
        const int j = it * 64 + lane;                      // 256B/wave contiguous loads
        const float w = Wr[j];
        const float a = Ar[j];
        float sa, ca;
        __sincosf(a, &sa, &ca);
        const float A  = w * ca;   // W*cos(alpha)
        const float Bq = w * sa;   // W*sin(alpha)
        const uint4 t = table[j];                          // one ds_read_b128, no conflict
        const uint32_t tw[4] = {t.x, t.y, t.z, t.w};
        #pragma unroll
        for (int d = 0; d < 4; ++d) {
            const float s = __uint_as_float(tw[d] << 16);
            const float c = __uint_as_float(tw[d] & 0xffff0000u);
            re[d] = fmaf(A,  c, re[d]);
            re[d] = fmaf(Bq, s, re[d]);
            im[d] = fmaf(A,  s, im[d]);
            im[d] = fmaf(-Bq, c, im[d]);
        }
    }

    // ---- Reduction: 6-stage butterfly over 64 lanes, 8 accumulators ----
    // once per row (~400 cyc) -- replaces the 32 KB LDS transpose scratch
    #pragma unroll
    for (int stage = 1; stage < 64; stage <<= 1) {
        #pragma unroll
        for (int d = 0; d < 4; ++d) {
            re[d] += __shfl_xor(re[d], stage, 64);
            im[d] += __shfl_xor(im[d], stage, 64);
        }
    }
    // every lane now holds all 8 row totals

    if (lane == 0) {
        const size_t obase = ((size_t)b * N_NODES + i) * 4;
        const float4 th4 = *(const float4*)(thb + (size_t)i * 4);
        const float4 g4  = *(const float4*)(gamma + obase);
        const float thd[4] = {th4.x, th4.y, th4.z, th4.w};
        const float gd[4]  = {g4.x, g4.y, g4.z, g4.w};
        float t[4];
        float s2 = 0.0f;
        #pragma unroll
        for (int d = 0; d < 4; ++d) {
            float s_i, c_i;
            __sincosf(thd[d], &s_i, &c_i);
            const float coup = (c_i * im[d] - s_i * re[d]) * (1.0f / (float)N_NODES);
            t[d] = gd[d] + coup;   // theta + (gamma-theta) + coupling  (DT=ATTR=1)
            s2 = fmaf(t[d], t[d], s2);
        }
        const float inv = 1.0f / fmaxf(sqrtf(s2), 1e-6f);
        *(float4*)(out + obase) = make_float4(t[0]*inv, t[1]*inv, t[2]*inv, t[3]*inv);
    }
}

extern "C" void kernel_launch(void* const* d_in, const int* in_sizes, int n_in,
                              void* d_out, int out_size, void* d_ws, size_t ws_size,
                              hipStream_t stream) {
    const float* theta = (const float*)d_in[0];
    const float* gamma = (const float*)d_in[1];
    const float* W     = (const float*)d_in[2];
    const float* alpha = (const float*)d_in[3];
    float* out = (float*)d_out;

    const int grid = (N_BATCH * N_NODES) / ROWS_PER_BLOCK;  // 1024 blocks = 4/CU
    hipLaunchKernelGGL(kuramoto_kernel, dim3(grid), dim3(THREADS), 0, stream,
                       theta, gamma, W, alpha, out);
}